// Round 7
// baseline (297.103 us; speedup 1.0000x reference)
//
#include <hip/hip_runtime.h>
#include <hip/hip_bf16.h>

typedef _Float16 half8 __attribute__((ext_vector_type(8)));
typedef _Float16 half4v __attribute__((ext_vector_type(4)));
typedef float f32x4 __attribute__((ext_vector_type(4)));

#define SWZ(byte, r) ((unsigned)(byte) ^ ((((unsigned)(r)) & 7u) << 4))

constexpr int Bb = 128;     // batches
constexpr int Nn = 2048;    // nodes
constexpr int Ee = 128;     // embed

// workspace layout (bytes)
constexpr size_t OFF_W    = 0;                                   // 4 tiles x 32768 (f16, pre-swizzled)
constexpr size_t OFF_PROJ = 131072;                              // [B*N][128] f16, pre-swizzled, 64 MiB
constexpr size_t OFF_UT   = OFF_PROJ + (size_t)Bb * Nn * Ee * 2; // [B*N] f32
constexpr size_t OFF_UT2  = OFF_UT   + (size_t)Bb * Nn * 4;
constexpr size_t OFF_HP   = OFF_UT2  + (size_t)Bb * Nn * 4;      // [B][16][128] f32 partial h_i

// async global->LDS copy, 16 B per lane (contiguous lane*16 pattern — HW-compatible)
__device__ __forceinline__ void cp16(void* lds, const void* g) {
    __builtin_amdgcn_global_load_lds(
        (const __attribute__((address_space(1))) unsigned int*)g,
        (__attribute__((address_space(3))) unsigned int*)lds, 16, 0, 0);
}

__device__ __forceinline__ float fast_tanh(float x) {
    float e = __expf(2.0f * x);
    return 1.0f - 2.0f * __builtin_amdgcn_rcpf(e + 1.0f);
}

// ---------------- prep: convert weights fp32 -> f16, pre-swizzled tiles ----------------
__global__ __launch_bounds__(256) void k_prep(const float* __restrict__ Ws,
                                              const float* __restrict__ Wa,
                                              const float* __restrict__ Wc,
                                              char* __restrict__ wdst)
{
    int id = blockIdx.x * 256 + threadIdx.x;
    for (int i = id; i < 65536; i += 64 * 256) {
        int mat = i >> 14;
        int rem = i & 16383;
        int r = rem >> 7, c = rem & 127;
        float v;
        if      (mat == 0) v = Ws[r * 128 + c];
        else if (mat == 1) v = Wa[r * 128 + c];
        else if (mat == 2) v = Wc[r * 256 + c];
        else               v = Wc[r * 256 + 128 + c];
        unsigned off = SWZ((unsigned)((r * 128 + c) * 2), r);
        *reinterpret_cast<_Float16*>(wdst + (size_t)mat * 32768 + off) = (_Float16)v;
    }
}

// ---------------- pass1: 512 blocks x 256 thr, 80KB LDS -> 2 blocks/CU ------------------
// per block: 8 tiles of 64 rows; proj = inst@Ws^T + bs ; u_t = v_a . tanh(proj@Wa^T + ba)
__global__ __launch_bounds__(256) void k_pass1(const float* __restrict__ inst,
                                               const char* __restrict__ wtiles,
                                               const float* __restrict__ bs,
                                               const float* __restrict__ ba,
                                               const float* __restrict__ va,
                                               char* __restrict__ projg,
                                               float* __restrict__ ut)
{
    __shared__ _Float16 ldsW[2 * 16384];   // 64 KB: W_s | W_a (pre-swizzled)
    __shared__ _Float16 buf[8192];         // 16 KB: inst tile -> proj tile (single buffer)

    const int tid  = threadIdx.x;
    const int lane = tid & 63;
    const int w    = tid >> 6;        // 4 waves
    const int l15  = lane & 15;
    const int kg   = lane >> 4;
    const int arow = w * 16 + l15;    // 0..63

    // stage W_s + W_a (64 KB) async, once per block
    #pragma unroll
    for (int i = 0; i < 16; ++i) {
        unsigned o = (unsigned)((i * 256 + tid) * 16);
        cp16((char*)ldsW + o, wtiles + o);
    }

    const size_t tile0 = (size_t)blockIdx.x * 8;
    float4 v[8];
    {   // tile 0 fp32 -> regs
        const float* src = inst + tile0 * 64 * 128;
        #pragma unroll
        for (int i = 0; i < 8; ++i)
            v[i] = *reinterpret_cast<const float4*>(src + (size_t)(i * 256 + tid) * 4);
    }

    for (int it = 0; it < 8; ++it) {
        const size_t row0 = (tile0 + it) * 64;

        // convert current tile regs -> buf (swizzled f16)
        #pragma unroll
        for (int i = 0; i < 8; ++i) {
            int f = i * 256 + tid;            // float4 index, 2048 total (64 rows x 32)
            int r = f >> 5, c4 = f & 31;
            half4v h = { (_Float16)v[i].x, (_Float16)v[i].y, (_Float16)v[i].z, (_Float16)v[i].w };
            *reinterpret_cast<half4v*>((char*)buf + SWZ(r * 256 + c4 * 8, r)) = h;
        }
        __syncthreads();   // B1: buf ready (iter0: + weights)

        // issue next-tile loads (drain at B2, covered by GEMM1 + other block)
        if (it + 1 < 8) {
            const float* src = inst + (row0 + 64) * 128;
            #pragma unroll
            for (int i = 0; i < 8; ++i)
                v[i] = *reinterpret_cast<const float4*>(src + (size_t)(i * 256 + tid) * 4);
        }

        // GEMM1: proj = inst @ Ws^T
        f32x4 acc[8];
        #pragma unroll
        for (int fr = 0; fr < 8; ++fr) acc[fr] = f32x4{0.f, 0.f, 0.f, 0.f};
        #pragma unroll
        for (int kk = 0; kk < 4; ++kk) {
            half8 af = *reinterpret_cast<const half8*>(
                (char*)buf + SWZ(arow * 256 + kk * 64 + kg * 16, arow));
            #pragma unroll
            for (int fr = 0; fr < 8; ++fr) {
                int br = fr * 16 + l15;
                half8 bf = *reinterpret_cast<const half8*>(
                    (char*)ldsW + SWZ(br * 256 + kk * 64 + kg * 16, br));
                acc[fr] = __builtin_amdgcn_mfma_f32_16x16x32_f16(af, bf, acc[fr], 0, 0, 0);
            }
        }
        __syncthreads();   // B2: buf reads done

        // proj(+bias) overwrites buf
        #pragma unroll
        for (int fr = 0; fr < 8; ++fr) {
            int e = fr * 16 + l15;
            float bsv = bs[e];
            #pragma unroll
            for (int j = 0; j < 4; ++j) {
                int r = w * 16 + kg * 4 + j;
                *reinterpret_cast<_Float16*>((char*)buf + SWZ(r * 256 + e * 2, r)) =
                    (_Float16)(acc[fr][j] + bsv);
            }
        }
        __syncthreads();   // B3: proj ready

        // GEMM2: tac = proj @ Wa^T
        f32x4 tac[8];
        #pragma unroll
        for (int fr = 0; fr < 8; ++fr) tac[fr] = f32x4{0.f, 0.f, 0.f, 0.f};
        #pragma unroll
        for (int kk = 0; kk < 4; ++kk) {
            half8 af = *reinterpret_cast<const half8*>(
                (char*)buf + SWZ(arow * 256 + kk * 64 + kg * 16, arow));
            #pragma unroll
            for (int fr = 0; fr < 8; ++fr) {
                int br = fr * 16 + l15;
                half8 bf = *reinterpret_cast<const half8*>(
                    (char*)ldsW + 32768 + SWZ(br * 256 + kk * 64 + kg * 16, br));
                tac[fr] = __builtin_amdgcn_mfma_f32_16x16x32_f16(af, bf, tac[fr], 0, 0, 0);
            }
        }

        // copy proj tile (pre-swizzled) -> global
        {
            char* dst = projg + row0 * 256;
            #pragma unroll
            for (int i = 0; i < 4; ++i) {
                unsigned o = (unsigned)((i * 256 + tid) * 16);
                *reinterpret_cast<uint4*>(dst + o) =
                    *reinterpret_cast<const uint4*>((const char*)buf + o);
            }
        }

        // epilogue: u_t = v_a . tanh(tac + ba)
        float u[4] = {0.f, 0.f, 0.f, 0.f};
        #pragma unroll
        for (int fr = 0; fr < 8; ++fr) {
            int fcol = fr * 16 + l15;
            float vav = va[fcol], bav = ba[fcol];
            #pragma unroll
            for (int j = 0; j < 4; ++j)
                u[j] += vav * fast_tanh(tac[fr][j] + bav);
        }
        #pragma unroll
        for (int d = 1; d < 16; d <<= 1) {
            #pragma unroll
            for (int j = 0; j < 4; ++j) u[j] += __shfl_xor(u[j], d);
        }
        if (l15 == 0) {
            #pragma unroll
            for (int j = 0; j < 4; ++j)
                ut[row0 + w * 16 + kg * 4 + j] = u[j];
        }
        __syncthreads();   // B4: buf reads done before next convert
    }
}

// ---------------- pass2: 512 blocks x 256 thr, 80KB -> 2 blocks/CU ----------------------
// block = (batch, quarter); softmax(u_t[batch]) once; 8 tiles of 64 rows, reg-prefetched.
__global__ __launch_bounds__(256) void k_pass2(const char* __restrict__ projg,
                                               const char* __restrict__ wtiles,
                                               const float* __restrict__ bc,
                                               const float* __restrict__ vc,
                                               const float* __restrict__ ut,
                                               float* __restrict__ ut2)
{
    __shared__ _Float16 ldsW[2 * 16384];   // 64 KB: W_c1 | W_c2
    __shared__ _Float16 buf[8192];         // 16 KB proj tile (scratch-aliased pre-DMA)
    float* scratch = reinterpret_cast<float*>(buf);

    const int tid  = threadIdx.x;
    const int lane = tid & 63;
    const int w    = tid >> 6;
    const int l15  = lane & 15;
    const int kg   = lane >> 4;
    const int arow = w * 16 + l15;
    const int bid  = blockIdx.x;
    const int batch = bid >> 2, quarter = bid & 3;

    // weights DMA first (drained by softmax's first barrier — once per block, cheap)
    #pragma unroll
    for (int i = 0; i < 16; ++i) {
        unsigned o = (unsigned)((i * 256 + tid) * 16);
        cp16((char*)ldsW + o, wtiles + 65536 + o);
    }

    // softmax(u_t[batch]), scratch in buf region (pre-DMA)
    const float* utb = ut + (size_t)batch * Nn;
    float4 x0 = *reinterpret_cast<const float4*>(utb + tid * 8);
    float4 x1 = *reinterpret_cast<const float4*>(utb + tid * 8 + 4);
    float m = fmaxf(fmaxf(fmaxf(x0.x, x0.y), fmaxf(x0.z, x0.w)),
                    fmaxf(fmaxf(x1.x, x1.y), fmaxf(x1.z, x1.w)));
    #pragma unroll
    for (int d = 1; d < 64; d <<= 1) m = fmaxf(m, __shfl_xor(m, d));
    if (lane == 0) scratch[w] = m;
    __syncthreads();
    float M = fmaxf(fmaxf(scratch[0], scratch[1]), fmaxf(scratch[2], scratch[3]));
    float e[8] = { __expf(x0.x - M), __expf(x0.y - M), __expf(x0.z - M), __expf(x0.w - M),
                   __expf(x1.x - M), __expf(x1.y - M), __expf(x1.z - M), __expf(x1.w - M) };
    float s = 0.f;
    #pragma unroll
    for (int i = 0; i < 8; ++i) s += e[i];
    #pragma unroll
    for (int d = 1; d < 64; d <<= 1) s += __shfl_xor(s, d);
    __syncthreads();
    if (lane == 0) scratch[4 + w] = s;
    __syncthreads();
    float invS = 1.0f / (scratch[4] + scratch[5] + scratch[6] + scratch[7]);
    // a_t for this block's 512 rows -> scratch[8..519]
    if ((tid >> 6) == quarter * 4 / 4 && tid >= quarter * 64 && tid < quarter * 64 + 64) {
        int base = tid * 8 - quarter * 512;
        #pragma unroll
        for (int k = 0; k < 8; ++k) scratch[8 + base + k] = e[k] * invS;
    }
    __syncthreads();
    float aj[8][4];
    #pragma unroll
    for (int t = 0; t < 8; ++t) {
        #pragma unroll
        for (int j = 0; j < 4; ++j)
            aj[t][j] = scratch[8 + t * 64 + w * 16 + kg * 4 + j];
    }
    __syncthreads();   // scratch reads done -> buf free for DMA

    const char* psrc = projg + ((size_t)batch * Nn + (size_t)quarter * 512) * 256;
    // tile 0 DMA
    #pragma unroll
    for (int i = 0; i < 4; ++i) {
        unsigned o = (unsigned)((i * 256 + tid) * 16);
        cp16((char*)buf + o, psrc + o);
    }

    uint4 pv[4];
    #pragma unroll
    for (int t = 0; t < 8; ++t) {
        __syncthreads();   // drain: buf = proj(t)

        if (t + 1 < 8) {   // reg-stage next tile (covered by GEMM below)
            const char* nsrc = psrc + (size_t)(t + 1) * 16384;
            #pragma unroll
            for (int i = 0; i < 4; ++i)
                pv[i] = *reinterpret_cast<const uint4*>(nsrc + (i * 256 + tid) * 16);
        }

        f32x4 u1[8], u2[8];
        #pragma unroll
        for (int fr = 0; fr < 8; ++fr) { u1[fr] = f32x4{0.f,0.f,0.f,0.f}; u2[fr] = f32x4{0.f,0.f,0.f,0.f}; }
        #pragma unroll
        for (int kk = 0; kk < 4; ++kk) {
            half8 af = *reinterpret_cast<const half8*>(
                (char*)buf + SWZ(arow * 256 + kk * 64 + kg * 16, arow));
            #pragma unroll
            for (int fr = 0; fr < 8; ++fr) {
                int br = fr * 16 + l15;
                half8 bf1 = *reinterpret_cast<const half8*>(
                    (char*)ldsW + SWZ(br * 256 + kk * 64 + kg * 16, br));
                u1[fr] = __builtin_amdgcn_mfma_f32_16x16x32_f16(af, bf1, u1[fr], 0, 0, 0);
                half8 bf2 = *reinterpret_cast<const half8*>(
                    (char*)ldsW + 32768 + SWZ(br * 256 + kk * 64 + kg * 16, br));
                u2[fr] = __builtin_amdgcn_mfma_f32_16x16x32_f16(af, bf2, u2[fr], 0, 0, 0);
            }
        }

        float u[4] = {0.f, 0.f, 0.f, 0.f};
        #pragma unroll
        for (int fr = 0; fr < 8; ++fr) {
            int fcol = fr * 16 + l15;
            float vcv = vc[fcol], bcv = bc[fcol];
            #pragma unroll
            for (int j = 0; j < 4; ++j)
                u[j] += vcv * fast_tanh(u1[fr][j] + aj[t][j] * u2[fr][j] + bcv);
        }
        #pragma unroll
        for (int d = 1; d < 16; d <<= 1) {
            #pragma unroll
            for (int j = 0; j < 4; ++j) u[j] += __shfl_xor(u[j], d);
        }
        if (l15 == 0) {
            #pragma unroll
            for (int j = 0; j < 4; ++j)
                ut2[(size_t)batch * Nn + (size_t)quarter * 512 + t * 64 + w * 16 + kg * 4 + j] = u[j];
        }
        __syncthreads();   // buf reads done
        if (t + 1 < 8) {   // write staged tile into buf
            #pragma unroll
            for (int i = 0; i < 4; ++i)
                *reinterpret_cast<uint4*>((char*)buf + (i * 256 + tid) * 16) = pv[i];
        }
    }
}

// ---------------- k_hi: fused softmax(prob) + partial h_i -------------------------------
__global__ __launch_bounds__(256) void k_hi(const float* __restrict__ ut2,
                                            const char* __restrict__ projg,
                                            float* __restrict__ hpart)
{
    __shared__ float pw[128];
    __shared__ float hp[16][128];
    __shared__ float redm[4], reds[4];

    const int bid = blockIdx.x;
    const int b = bid >> 4, chunk = bid & 15;
    const int n0 = chunk * 128;
    const int tid = threadIdx.x;
    const int lane = tid & 63, w = tid >> 6;

    // softmax(u_t_2[b]) — redundant per block
    const float* u2b = ut2 + (size_t)b * Nn;
    float4 x0 = *reinterpret_cast<const float4*>(u2b + tid * 8);
    float4 x1 = *reinterpret_cast<const float4*>(u2b + tid * 8 + 4);
    float m = fmaxf(fmaxf(fmaxf(x0.x, x0.y), fmaxf(x0.z, x0.w)),
                    fmaxf(fmaxf(x1.x, x1.y), fmaxf(x1.z, x1.w)));
    #pragma unroll
    for (int d = 1; d < 64; d <<= 1) m = fmaxf(m, __shfl_xor(m, d));
    if (lane == 0) redm[w] = m;
    __syncthreads();
    float M = fmaxf(fmaxf(redm[0], redm[1]), fmaxf(redm[2], redm[3]));
    float e[8] = { __expf(x0.x - M), __expf(x0.y - M), __expf(x0.z - M), __expf(x0.w - M),
                   __expf(x1.x - M), __expf(x1.y - M), __expf(x1.z - M), __expf(x1.w - M) };
    float s = 0.f;
    #pragma unroll
    for (int i = 0; i < 8; ++i) s += e[i];
    #pragma unroll
    for (int d = 1; d < 64; d <<= 1) s += __shfl_xor(s, d);
    if (lane == 0) reds[w] = s;
    __syncthreads();
    float inv = 1.0f / (reds[0] + reds[1] + reds[2] + reds[3]);
    if ((tid >> 4) == chunk) {
        int base = (tid & 15) * 8;
        #pragma unroll
        for (int k = 0; k < 8; ++k) pw[base + k] = e[k] * inv;
    }
    __syncthreads();

    const int rg = tid >> 4, c16 = tid & 15;
    const char* pb = projg + ((size_t)b * Nn + n0) * 256;
    float acc[8] = {0.f,0.f,0.f,0.f,0.f,0.f,0.f,0.f};
    #pragma unroll
    for (int itn = 0; itn < 8; ++itn) {
        int nl = rg + itn * 16;
        float wgt = pw[nl];
        unsigned off = (unsigned)(nl * 256 + ((c16 * 16) ^ ((nl & 7) << 4)));
        half8 ph = *reinterpret_cast<const half8*>(pb + off);
        #pragma unroll
        for (int j = 0; j < 8; ++j) acc[j] += wgt * (float)ph[j];
    }
    #pragma unroll
    for (int j = 0; j < 8; ++j) hp[rg][c16 * 8 + j] = acc[j];
    __syncthreads();
    if (tid < 128) {
        float s2 = 0.f;
        #pragma unroll
        for (int k = 0; k < 16; ++k) s2 += hp[k][tid];
        hpart[((size_t)b * 16 + chunk) * 128 + tid] = s2;
    }
}

// ---------------- k_head: h_i reduce + MLP head -----------------------------------------
__global__ __launch_bounds__(128) void k_head(const float* __restrict__ hpart,
                                              const float* __restrict__ W1,
                                              const float* __restrict__ b1,
                                              const float* __restrict__ W2,
                                              const float* __restrict__ b2,
                                              float* __restrict__ out)
{
    __shared__ float h[128];
    __shared__ float o1[128];
    const int b = blockIdx.x, tid = threadIdx.x;

    float s = 0.f;
    #pragma unroll
    for (int c = 0; c < 16; ++c) s += hpart[((size_t)b * 16 + c) * 128 + tid];
    h[tid] = s;
    __syncthreads();

    const float* wr = W1 + tid * 128;
    float o = b1[tid];
    #pragma unroll 8
    for (int e = 0; e < 128; e += 4) {
        float4 wv = *reinterpret_cast<const float4*>(wr + e);
        o += wv.x * h[e] + wv.y * h[e+1] + wv.z * h[e+2] + wv.w * h[e+3];
    }
    o1[tid] = fmaxf(o, 0.f);
    __syncthreads();

    if (tid < 64) {
        float p = o1[tid] * W2[tid] + o1[tid + 64] * W2[tid + 64];
        #pragma unroll
        for (int d = 1; d < 64; d <<= 1) p += __shfl_xor(p, d);
        if (tid == 0) out[b] = p + b2[0];
    }
}

// ---------------------------------------------------------------------------------------
extern "C" void kernel_launch(void* const* d_in, const int* in_sizes, int n_in,
                              void* d_out, int out_size, void* d_ws, size_t ws_size,
                              hipStream_t stream)
{
    const float* inst = (const float*)d_in[0];
    const float* Ws   = (const float*)d_in[1];
    const float* bs   = (const float*)d_in[2];
    const float* Wa   = (const float*)d_in[3];
    const float* ba   = (const float*)d_in[4];
    const float* va   = (const float*)d_in[5];
    const float* Wc   = (const float*)d_in[6];
    const float* bc   = (const float*)d_in[7];
    const float* vc   = (const float*)d_in[8];
    const float* W1   = (const float*)d_in[9];
    const float* b1   = (const float*)d_in[10];
    const float* W2   = (const float*)d_in[11];
    const float* b2   = (const float*)d_in[12];
    float* out = (float*)d_out;

    char*  ws     = (char*)d_ws;
    char*  wtiles = ws + OFF_W;
    char*  projg  = ws + OFF_PROJ;
    float* ut     = (float*)(ws + OFF_UT);
    float* ut2    = (float*)(ws + OFF_UT2);
    float* hpart  = (float*)(ws + OFF_HP);

    hipLaunchKernelGGL(k_prep,  dim3(64),      dim3(256), 0, stream, Ws, Wa, Wc, wtiles);
    hipLaunchKernelGGL(k_pass1, dim3(512),     dim3(256), 0, stream, inst, wtiles, bs, ba, va, projg, ut);
    hipLaunchKernelGGL(k_pass2, dim3(512),     dim3(256), 0, stream, projg, wtiles, bc, vc, ut, ut2);
    hipLaunchKernelGGL(k_hi,    dim3(Bb * 16), dim3(256), 0, stream, ut2, projg, hpart);
    hipLaunchKernelGGL(k_head,  dim3(Bb),      dim3(128), 0, stream, hpart, W1, b1, W2, b2, out);
}